// Round 1
// baseline (623.895 us; speedup 1.0000x reference)
//
#include <hip/hip_runtime.h>

#define THRESH 0.1f

// Input: 96 planes (32*3) of 1024x1024 fp32.
// Each wave (64 lanes) processes a strip of 4 horizontally adjacent 16x16 blocks.
// Lane l owns one image column: block j4*4 + l/16, column l%16, all 16 rows in regs.
__global__ __launch_bounds__(256) void wht16_kernel(const float* __restrict__ in,
                                                    float* __restrict__ out) {
    const int g = blockIdx.x * 256 + threadIdx.x;
    const int lane = g & 63;
    const int strip = g >> 6;            // 0 .. 98303
    const int p = strip >> 10;           // plane 0..95
    const int rem = strip & 1023;
    const int i = rem >> 4;              // block-row 0..63
    const int j4 = rem & 15;             // group of 4 block-cols, 0..15

    // ---- load: lane reads its column (16 rows, stride 1024 floats) ----
    // per load instruction the wave touches 64 consecutive floats (256 B coalesced)
    const long long in_base = (long long)p * 1048576
                            + (long long)(i * 16) * 1024
                            + (long long)(j4 * 64 + lane);
    float v[16];
#pragma unroll
    for (int r = 0; r < 16; ++r)
        v[r] = in[in_base + (long long)r * 1024];

    // ---- column WHT (along r), in-register butterflies, fully unrolled ----
#pragma unroll
    for (int m = 1; m < 16; m <<= 1) {
#pragma unroll
        for (int r = 0; r < 16; ++r) {
            if (!(r & m)) {
                const float a = v[r];
                const float b = v[r | m];
                v[r]     = a + b;
                v[r | m] = a - b;
            }
        }
    }

    // ---- row WHT (along cc = lane&15), shuffle butterflies within 16-lane group ----
#pragma unroll
    for (int m = 1; m < 16; m <<= 1) {
        const bool upper = (lane & m) != 0;
#pragma unroll
        for (int r = 0; r < 16; ++r) {
            const float partner = __shfl_xor(v[r], m, 64);
            v[r] = upper ? (partner - v[r]) : (v[r] + partner);
        }
    }

    // ---- scale (Hn = H/4 on both sides -> 1/16), threshold, store blocked ----
    // out[plane][i][j][r][cc], block chunk = 256 contiguous floats
    const int j = j4 * 4 + (lane >> 4);
    const long long out_base = ((long long)((p * 64 + i) * 64 + j)) * 256 + (lane & 15);
#pragma unroll
    for (int r = 0; r < 16; ++r) {
        float x = v[r] * 0.0625f;
        if (fabsf(x) < THRESH) x = 0.0f;
        out[out_base + r * 16] = x;
    }
}

extern "C" void kernel_launch(void* const* d_in, const int* in_sizes, int n_in,
                              void* d_out, int out_size, void* d_ws, size_t ws_size,
                              hipStream_t stream) {
    const float* in = (const float*)d_in[0];
    float* out = (float*)d_out;
    // total elements = 96 * 1024 * 1024; each thread handles 16 (one block column)
    const long long n = (long long)in_sizes[0];
    const int total_threads = (int)(n / 16);          // 6,291,456
    const int blocks = total_threads / 256;           // 24,576
    wht16_kernel<<<blocks, 256, 0, stream>>>(in, out);
}